// Round 8
// baseline (606.970 us; speedup 1.0000x reference)
//
#include <hip/hip_runtime.h>
#include <hip/hip_bf16.h>

// ---------------------------------------------------------------------------
// Causal MHA. B=2, S=2048, D=1024, H=16, Dh=64. Inputs fp32, output fp32.
// Internal bf16 MFMA.
// Memory plan (ws 24 MB, d_out 16 MB):
//   d_out[0:8MB]   Q   (B,H,S,Dh) bf16     d_out[8:16MB]  xb (4096,1024) bf16
//   ws[0:8MB]      K   (B,H,S,Dh) bf16 (dead after attn -> Wo-bf16)
//   ws[8:16MB]     VT  (B,H,Dh,S) bf16
//   ws[16:24MB]    Wq/Wk/Wv bf16 during qkv, then ATT (B,S,D) bf16
// ---------------------------------------------------------------------------

typedef __bf16 bf16x8 __attribute__((ext_vector_type(8)));
typedef float floatx4 __attribute__((ext_vector_type(4)));
typedef float floatx16 __attribute__((ext_vector_type(16)));

#define MFMA16(A, B, C) __builtin_amdgcn_mfma_f32_16x16x32_bf16((A), (B), (C), 0, 0, 0)
#define MFMA32(A, B, C) __builtin_amdgcn_mfma_f32_32x32x16_bf16((A), (B), (C), 0, 0, 0)

#define S_LEN 2048
#define D_MODEL 1024
#define NHEAD 16
#define DHEAD 64
#define NTOK 4096
#define NEG_SENTINEL (-1.0e30f)

__device__ __forceinline__ short f2bf(float f) {
  union { float f; unsigned u; } v; v.f = f;
  unsigned r = v.u + 0x7fffu + ((v.u >> 16) & 1u);
  return (short)(r >> 16);
}
__device__ __forceinline__ bf16x8 ld_frag(const short* p) {
  return *(const bf16x8*)p;
}
// async global->LDS, 16B per lane; LDS dst is wave-uniform base + lane*16.
__device__ __forceinline__ void gl_lds(const short* g, short* l) {
  __builtin_amdgcn_global_load_lds(
      (const __attribute__((address_space(1))) void*)g,
      (__attribute__((address_space(3))) void*)l, 16, 0, 0);
}

// ---------------------------------------------------------------------------
// fp32 -> bf16 bulk converts.
// ---------------------------------------------------------------------------
__global__ __launch_bounds__(256) void cvt4_kernel(
    const float* __restrict__ x, const float* __restrict__ wq,
    const float* __restrict__ wk, const float* __restrict__ wv,
    short* __restrict__ xb, short* __restrict__ wqb,
    short* __restrict__ wkb, short* __restrict__ wvb) {
  const int y = blockIdx.y;
  const float* src = (y == 0) ? x : (y == 1) ? wq : (y == 2) ? wk : wv;
  short* dst = (y == 0) ? xb : (y == 1) ? wqb : (y == 2) ? wkb : wvb;
  const int n4 = ((y == 0) ? NTOK * D_MODEL : D_MODEL * D_MODEL) >> 2;
  for (int i = blockIdx.x * 256 + threadIdx.x; i < n4; i += gridDim.x * 256) {
    float4 v = ((const float4*)src)[i];
    short4 o;
    o.x = f2bf(v.x); o.y = f2bf(v.y); o.z = f2bf(v.z); o.w = f2bf(v.w);
    ((short4*)dst)[i] = o;
  }
}
__global__ __launch_bounds__(256) void cvt1_kernel(
    const float* __restrict__ src, short* __restrict__ dst, int n4) {
  for (int i = blockIdx.x * 256 + threadIdx.x; i < n4; i += gridDim.x * 256) {
    float4 v = ((const float4*)src)[i];
    short4 o;
    o.x = f2bf(v.x); o.y = f2bf(v.y); o.z = f2bf(v.z); o.w = f2bf(v.w);
    ((short4*)dst)[i] = o;
  }
}

// ---------------------------------------------------------------------------
// QKV + RoPE, m97-style 128x128 tile, global_load_lds staging, 4 waves.
// grid (256, 3): blockIdx.x -> 32 M-tiles x 8 N-tiles; y: 0=Q,1=K,2=V.
// ---------------------------------------------------------------------------
__global__ __launch_bounds__(256) void qkv_rope_kernel(
    const short* __restrict__ xb,
    const short* __restrict__ Wqb, const short* __restrict__ Wkb,
    const short* __restrict__ Wvb,
    short* __restrict__ qws, short* __restrict__ kws, short* __restrict__ vtws) {
  __shared__ short As[128 * 32];
  __shared__ short Bs[128 * 32];
  const int tid = threadIdx.x;
  const int lane = tid & 63, wave = tid >> 6;
  const int col = lane & 15, quad = lane >> 4;
  const int gemm = blockIdx.y;
  const int m0 = (blockIdx.x >> 3) * 128;
  const int n0 = (blockIdx.x & 7) * 128;
  const int wm = (wave >> 1) * 64, wn = (wave & 1) * 64;
  const short* W = (gemm == 0) ? Wqb : (gemm == 1) ? Wkb : Wvb;

  floatx4 acc[4][4];
#pragma unroll
  for (int i = 0; i < 4; ++i)
#pragma unroll
    for (int j = 0; j < 4; ++j) acc[i][j] = (floatx4){0.f, 0.f, 0.f, 0.f};

  const short* asrc = xb + (size_t)(m0 + (tid >> 2)) * D_MODEL + (tid & 3) * 8;
  const short* bsrc = W + (size_t)(n0 + (tid >> 2)) * D_MODEL + (tid & 3) * 8;

  for (int k0 = 0; k0 < D_MODEL; k0 += 32) {
    __syncthreads();  // previous iteration's LDS reads done
    gl_lds(asrc + k0, &As[tid * 8]);
    gl_lds(asrc + (size_t)64 * D_MODEL + k0, &As[2048 + tid * 8]);
    gl_lds(bsrc + k0, &Bs[tid * 8]);
    gl_lds(bsrc + (size_t)64 * D_MODEL + k0, &Bs[2048 + tid * 8]);
    __syncthreads();  // drains vmcnt -> staged data visible
    bf16x8 a[4], b[4];
#pragma unroll
    for (int mt = 0; mt < 4; ++mt)
      a[mt] = ld_frag(&As[(wm + mt * 16 + col) * 32 + quad * 8]);
#pragma unroll
    for (int nt = 0; nt < 4; ++nt)
      b[nt] = ld_frag(&Bs[(wn + nt * 16 + col) * 32 + quad * 8]);
#pragma unroll
    for (int mt = 0; mt < 4; ++mt)
#pragma unroll
      for (int nt = 0; nt < 4; ++nt)
        acc[mt][nt] = MFMA16(a[mt], b[nt], acc[mt][nt]);
  }

  if (gemm == 2) {
#pragma unroll
    for (int mt = 0; mt < 4; ++mt)
#pragma unroll
      for (int nt = 0; nt < 4; ++nt) {
        int n = n0 + wn + nt * 16 + col;
        int h = n >> 6, dh = n & 63;
#pragma unroll
        for (int r = 0; r < 4; ++r) {
          int m = m0 + wm + mt * 16 + quad * 4 + r;
          int bb = m >> 11, s = m & (S_LEN - 1);
          vtws[((size_t)(bb * NHEAD + h) * DHEAD + dh) * S_LEN + s] = f2bf(acc[mt][nt][r]);
        }
      }
  } else {
    short* out = (gemm == 0) ? qws : kws;
    const float qscale = (gemm == 0) ? 0.125f : 1.0f;
#pragma unroll
    for (int mt = 0; mt < 4; ++mt)
#pragma unroll
      for (int nt = 0; nt < 4; ++nt) {
        int n = n0 + wn + nt * 16 + col;
        int h = n >> 6, dh = n & 63;
        int p = dh >> 1;
        float inv_freq = __expf(-0.28782313662425575f * (float)p);
#pragma unroll
        for (int r = 0; r < 4; ++r) {
          int m = m0 + wm + mt * 16 + quad * 4 + r;
          int s = m & (S_LEN - 1);
          float ang = (float)s * inv_freq;
          float sn, c;
          sincosf(ang, &sn, &c);
          float val = acc[mt][nt][r];
          float partner = __shfl_xor(val, 1);
          float o = ((dh & 1) == 0) ? (val * c - partner * sn)
                                    : (partner * sn + val * c);
          int bb = m >> 11;
          out[((size_t)(bb * NHEAD + h) * S_LEN + s) * DHEAD + dh] = f2bf(o * qscale);
        }
      }
  }
}

// ---------------------------------------------------------------------------
// Flash attention, 32x32x16 MFMA, transposed scores + transposed O.
// 1 wave/block, 32 q-rows/wave, 64 keys/iter. grid 2048 x 64.
//   S^T[key][q]: A=K(m=key), B=Q(n=q)  -> C col = q = lane&31 (softmax in-lane)
//   O^T[d][q]:   A=VT(m=d),  B=P(n=q)  -> C col = q (alpha/l rescale in-lane)
// P routed C->B layout via LDS [32 q][72] (144B rows, 16B aligned).
// ---------------------------------------------------------------------------
__global__ __launch_bounds__(64) void attn_kernel(
    const short* __restrict__ qws, const short* __restrict__ kws,
    const short* __restrict__ vtws, short* __restrict__ att) {
  const int lane = threadIdx.x;
  const int half = lane >> 5, l31 = lane & 31;
  const int qt = 63 - (blockIdx.x & 63);  // long blocks first
  const int h = (blockIdx.x >> 6) & (NHEAD - 1);
  const int b = blockIdx.x >> 10;
  const int q0 = qt * 32;

  __shared__ short P[32][72];

  const short* qbase = qws + (size_t)(b * NHEAD + h) * S_LEN * DHEAD;
  const short* kbase = kws + (size_t)(b * NHEAD + h) * S_LEN * DHEAD;
  const short* vbase = vtws + (size_t)(b * NHEAD + h) * DHEAD * S_LEN;

  // Q as B-operand: n=q=l31, k-chunk kc: k = kc*16 + half*8 + j
  bf16x8 qf[4];
#pragma unroll
  for (int kc = 0; kc < 4; ++kc)
    qf[kc] = ld_frag(qbase + (size_t)(q0 + l31) * DHEAD + kc * 16 + half * 8);

  float m_i = NEG_SENTINEL, l_i = 0.f;
  floatx16 ot[2] = {};  // O^T: rows d = dt*32 + (reg&3)+8*(reg>>2)+4*half, col q=l31

  const int nit = (q0 + 32 + 63) >> 6;
  for (int it = 0; it < nit; ++it) {
    const int kt = it * 64;
    // --- scores S^T (2 key-tiles of 32)
    floatx16 sc[2];
#pragma unroll
    for (int s = 0; s < 2; ++s) {
      if (kt + s * 32 <= q0 + 31) {  // wave-uniform: tile has >=1 unmasked key
        floatx16 a = {};
#pragma unroll
        for (int kc = 0; kc < 4; ++kc) {
          bf16x8 ka = ld_frag(kbase + (size_t)(kt + s * 32 + l31) * DHEAD + kc * 16 + half * 8);
          a = MFMA32(ka, qf[kc], a);
        }
        sc[s] = a;
      } else {
#pragma unroll
        for (int rg = 0; rg < 16; ++rg) sc[s][rg] = NEG_SENTINEL;
      }
    }
    // --- causal mask (wave-uniform skip for full tiles)
    if (kt + 63 > q0) {
#pragma unroll
      for (int s = 0; s < 2; ++s)
#pragma unroll
        for (int rg = 0; rg < 16; ++rg) {
          int key = kt + s * 32 + (rg & 3) + 8 * (rg >> 2) + 4 * half;
          if (key > q0 + l31) sc[s][rg] = NEG_SENTINEL;
        }
    }
    // --- online softmax over keys: 31 in-lane max + 1 shuffle
    float rm = sc[0][0];
#pragma unroll
    for (int rg = 1; rg < 16; ++rg) rm = fmaxf(rm, sc[0][rg]);
#pragma unroll
    for (int rg = 0; rg < 16; ++rg) rm = fmaxf(rm, sc[1][rg]);
    rm = fmaxf(rm, __shfl_xor(rm, 32));
    float mnew = fmaxf(m_i, rm);
    float alpha = __expf(m_i - mnew);  // iter 0: exp(-1e30)=0
    m_i = mnew;

    float rs = 0.f;
#pragma unroll
    for (int s = 0; s < 2; ++s)
#pragma unroll
      for (int g = 0; g < 4; ++g) {
        float p0 = __expf(sc[s][4 * g + 0] - mnew);
        float p1 = __expf(sc[s][4 * g + 1] - mnew);
        float p2 = __expf(sc[s][4 * g + 2] - mnew);
        float p3 = __expf(sc[s][4 * g + 3] - mnew);
        rs += (p0 + p1) + (p2 + p3);
        int kb = s * 32 + 8 * g + 4 * half;  // 4 consecutive keys
        *(unsigned*)&P[l31][kb] =
            (unsigned)(unsigned short)f2bf(p0) | ((unsigned)(unsigned short)f2bf(p1) << 16);
        *(unsigned*)&P[l31][kb + 2] =
            (unsigned)(unsigned short)f2bf(p2) | ((unsigned)(unsigned short)f2bf(p3) << 16);
      }
    rs += __shfl_xor(rs, 32);
    l_i = l_i * alpha + rs;
#pragma unroll
    for (int dt = 0; dt < 2; ++dt)
#pragma unroll
      for (int rg = 0; rg < 16; ++rg) ot[dt][rg] *= alpha;  // col=q: in-lane

    __syncthreads();
    // --- PV: O^T += VT * P^T ; B-frag (P) shared across both d-tiles
#pragma unroll
    for (int kc = 0; kc < 4; ++kc) {
      bf16x8 pb = ld_frag(&P[l31][kc * 16 + half * 8]);
#pragma unroll
      for (int dt = 0; dt < 2; ++dt) {
        bf16x8 va = ld_frag(vbase + (size_t)(dt * 32 + l31) * S_LEN + kt + kc * 16 + half * 8);
        ot[dt] = MFMA32(va, pb, ot[dt]);
      }
    }
    __syncthreads();
  }

  // --- epilogue: normalize (in-lane), transpose via LDS, coalesced store
  float inv = 1.0f / l_i;  // l_i >= 1
#pragma unroll
  for (int dt = 0; dt < 2; ++dt)
#pragma unroll
    for (int g = 0; g < 4; ++g) {
      int db = dt * 32 + 8 * g + 4 * half;  // 4 consecutive d
      float v0 = ot[dt][4 * g + 0] * inv, v1 = ot[dt][4 * g + 1] * inv;
      float v2 = ot[dt][4 * g + 2] * inv, v3 = ot[dt][4 * g + 3] * inv;
      *(unsigned*)&P[l31][db] =
          (unsigned)(unsigned short)f2bf(v0) | ((unsigned)(unsigned short)f2bf(v1) << 16);
      *(unsigned*)&P[l31][db + 2] =
          (unsigned)(unsigned short)f2bf(v2) | ((unsigned)(unsigned short)f2bf(v3) << 16);
    }
  __syncthreads();
  // row q=l31 holds O[q][0..63]; halves store 32 shorts each as 4x int4
  const int4* srcp = (const int4*)&P[l31][half * 32];
  int4* dstp = (int4*)(att + (size_t)(b * S_LEN + q0 + l31) * D_MODEL + h * DHEAD + half * 32);
#pragma unroll
  for (int i = 0; i < 4; ++i) dstp[i] = srcp[i];
}

// ---------------------------------------------------------------------------
// Output projection: out = att (bf16) @ Wo^T (bf16) -> fp32. m97-style tile.
// ---------------------------------------------------------------------------
__global__ __launch_bounds__(256) void out_gemm_kernel(
    const short* __restrict__ att, const short* __restrict__ Wob,
    float* __restrict__ out) {
  __shared__ short As[128 * 32];
  __shared__ short Bs[128 * 32];
  const int tid = threadIdx.x;
  const int lane = tid & 63, wave = tid >> 6;
  const int col = lane & 15, quad = lane >> 4;
  const int m0 = (blockIdx.x >> 3) * 128;
  const int n0 = (blockIdx.x & 7) * 128;
  const int wm = (wave >> 1) * 64, wn = (wave & 1) * 64;

  floatx4 acc[4][4];
#pragma unroll
  for (int i = 0; i < 4; ++i)
#pragma unroll
    for (int j = 0; j < 4; ++j) acc[i][j] = (floatx4){0.f, 0.f, 0.f, 0.f};

  const short* asrc = att + (size_t)(m0 + (tid >> 2)) * D_MODEL + (tid & 3) * 8;
  const short* bsrc = Wob + (size_t)(n0 + (tid >> 2)) * D_MODEL + (tid & 3) * 8;

  for (int k0 = 0; k0 < D_MODEL; k0 += 32) {
    __syncthreads();
    gl_lds(asrc + k0, &As[tid * 8]);
    gl_lds(asrc + (size_t)64 * D_MODEL + k0, &As[2048 + tid * 8]);
    gl_lds(bsrc + k0, &Bs[tid * 8]);
    gl_lds(bsrc + (size_t)64 * D_MODEL + k0, &Bs[2048 + tid * 8]);
    __syncthreads();
    bf16x8 a[4], b[4];
#pragma unroll
    for (int mt = 0; mt < 4; ++mt)
      a[mt] = ld_frag(&As[(wm + mt * 16 + col) * 32 + quad * 8]);
#pragma unroll
    for (int nt = 0; nt < 4; ++nt)
      b[nt] = ld_frag(&Bs[(wn + nt * 16 + col) * 32 + quad * 8]);
#pragma unroll
    for (int mt = 0; mt < 4; ++mt)
#pragma unroll
      for (int nt = 0; nt < 4; ++nt)
        acc[mt][nt] = MFMA16(a[mt], b[nt], acc[mt][nt]);
  }

#pragma unroll
  for (int mt = 0; mt < 4; ++mt)
#pragma unroll
    for (int nt = 0; nt < 4; ++nt) {
      int n = n0 + wn + nt * 16 + col;
#pragma unroll
      for (int r = 0; r < 4; ++r) {
        int m = m0 + wm + mt * 16 + quad * 4 + r;
        out[(size_t)m * D_MODEL + n] = acc[mt][nt][r];
      }
    }
}

// ---------------------------------------------------------------------------
extern "C" void kernel_launch(void* const* d_in, const int* in_sizes, int n_in,
                              void* d_out, int out_size, void* d_ws, size_t ws_size,
                              hipStream_t stream) {
  const float* x  = (const float*)d_in[0];
  const float* Wq = (const float*)d_in[2];
  const float* Wk = (const float*)d_in[3];
  const float* Wv = (const float*)d_in[4];
  const float* Wo = (const float*)d_in[5];
  float* out = (float*)d_out;

  const size_t TENS = (size_t)NTOK * D_MODEL;
  const size_t WELEM = (size_t)D_MODEL * D_MODEL;

  short* qws  = (short*)d_out;
  short* xb   = (short*)d_out + TENS;
  short* kws  = (short*)d_ws;
  short* vtws = kws + TENS;
  short* attws = vtws + TENS;
  short* wqb = attws;  // W-bf16 overlay in ATT region (dead once attn writes)
  short* wkb = wqb + WELEM;
  short* wvb = wkb + WELEM;
  short* wob = kws;    // K region, dead after attn

  cvt4_kernel<<<dim3(256, 4), 256, 0, stream>>>(x, Wq, Wk, Wv, xb, wqb, wkb, wvb);
  qkv_rope_kernel<<<dim3(256, 3), 256, 0, stream>>>(xb, wqb, wkb, wvb, qws, kws, vtws);
  attn_kernel<<<dim3(2048), 64, 0, stream>>>(qws, kws, vtws, attws);
  cvt1_kernel<<<dim3(256), 256, 0, stream>>>(Wo, wob, (int)(WELEM >> 2));
  out_gemm_kernel<<<dim3(256), 256, 0, stream>>>(attws, wob, out);
}